// Round 1
// baseline (2809.501 us; speedup 1.0000x reference)
//
#include <hip/hip_runtime.h>

static __device__ __forceinline__ float frelu(float v) { return v > 0.f ? v : 0.f; }

// ---------------- encoder conv1: 4x4 s2 p1, 3->64, bias+relu, 256^2 -> 128^2 ----
__global__ __launch_bounds__(256) void k_ew1(const float* __restrict__ x,
    const float* __restrict__ w, const float* __restrict__ bias, float* __restrict__ out)
{
    const int t = threadIdx.x;
    const int tile = blockIdx.x;          // 64 tiles (8x8) of 16x16 over 128x128
    const int bcg = blockIdx.y;           // b*8 + cg
    const int b = bcg >> 3, cg = bcg & 7;
    const int oy0 = (tile >> 3) << 4, ox0 = (tile & 7) << 4;
    const int tx = t & 15, ty = t >> 4;
    const int iy0 = 2 * oy0 - 1, ix0 = 2 * ox0 - 1;

    __shared__ float s_in[3 * 34 * 35];
    for (int i = t; i < 3 * 1156; i += 256) {
        int ci = i / 1156, r = (i % 1156) / 34, c = i % 34;
        int gy = iy0 + r, gx = ix0 + c;
        float v = 0.f;
        if ((unsigned)gy < 256u && (unsigned)gx < 256u)
            v = x[((b * 3 + ci) * 256 + gy) * 256 + gx];
        s_in[(ci * 34 + r) * 35 + c] = v;
    }
    __syncthreads();

    float acc[8];
#pragma unroll
    for (int i = 0; i < 8; ++i) acc[i] = 0.f;
#pragma unroll
    for (int ci = 0; ci < 3; ++ci)
#pragma unroll
        for (int ky = 0; ky < 4; ++ky)
#pragma unroll
            for (int kx = 0; kx < 4; ++kx) {
                float v = s_in[(ci * 34 + 2 * ty + ky) * 35 + 2 * tx + kx];
#pragma unroll
                for (int co = 0; co < 8; ++co)
                    acc[co] += v * w[((cg * 8 + co) * 3 + ci) * 16 + ky * 4 + kx];
            }
#pragma unroll
    for (int co = 0; co < 8; ++co) {
        int oc = cg * 8 + co;
        out[((b * 64 + oc) * 128 + oy0 + ty) * 128 + ox0 + tx] = frelu(acc[co] + bias[oc]);
    }
}

// ---------------- encoder conv2: 4x4 s2 p1, 64->128, bias+relu, 128^2 -> 64^2 ---
__global__ __launch_bounds__(256) void k_ew2(const float* __restrict__ in,
    const float* __restrict__ w, const float* __restrict__ bias, float* __restrict__ out)
{
    const int t = threadIdx.x;
    const int tile = blockIdx.x;          // 16 tiles (4x4) of 16x16 over 64x64
    const int bcg = blockIdx.y;           // b*16 + cg
    const int b = bcg >> 4, cg = bcg & 15;
    const int oy0 = (tile >> 2) << 4, ox0 = (tile & 3) << 4;
    const int tx = t & 15, ty = t >> 4;
    const int iy0 = 2 * oy0 - 1, ix0 = 2 * ox0 - 1;

    __shared__ float s_in[4 * 34 * 35];
    float acc[8];
#pragma unroll
    for (int i = 0; i < 8; ++i) acc[i] = 0.f;

    for (int cc = 0; cc < 16; ++cc) {
        __syncthreads();
        for (int i = t; i < 4 * 1156; i += 256) {
            int ci = i / 1156, r = (i % 1156) / 34, c = i % 34;
            int gy = iy0 + r, gx = ix0 + c;
            float v = 0.f;
            if ((unsigned)gy < 128u && (unsigned)gx < 128u)
                v = in[((b * 64 + cc * 4 + ci) * 128 + gy) * 128 + gx];
            s_in[(ci * 34 + r) * 35 + c] = v;
        }
        __syncthreads();
#pragma unroll
        for (int ci = 0; ci < 4; ++ci)
#pragma unroll
            for (int ky = 0; ky < 4; ++ky)
#pragma unroll
                for (int kx = 0; kx < 4; ++kx) {
                    float v = s_in[(ci * 34 + 2 * ty + ky) * 35 + 2 * tx + kx];
#pragma unroll
                    for (int co = 0; co < 8; ++co)
                        acc[co] += v * w[((cg * 8 + co) * 64 + cc * 4 + ci) * 16 + ky * 4 + kx];
                }
    }
#pragma unroll
    for (int co = 0; co < 8; ++co) {
        int oc = cg * 8 + co;
        out[((b * 128 + oc) * 64 + oy0 + ty) * 64 + ox0 + tx] = frelu(acc[co] + bias[oc]);
    }
}

// ---------------- generic 3x3 s1 p1 conv at 64x64 ------------------------------
template<int CIN, int COUT, bool RELU, bool HASBIAS>
__global__ __launch_bounds__(256) void k_conv3(const float* __restrict__ in,
    const float* __restrict__ w, const float* __restrict__ bias, float* __restrict__ out)
{
    const int t = threadIdx.x;
    const int tile = blockIdx.x;          // 16 tiles (4x4) of 16x16
    const int bcg = blockIdx.y;           // b*(COUT/8) + cg
    const int b = bcg / (COUT / 8), cg = bcg % (COUT / 8);
    const int oy0 = (tile >> 2) << 4, ox0 = (tile & 3) << 4;
    const int tx = t & 15, ty = t >> 4;
    const int iy0 = oy0 - 1, ix0 = ox0 - 1;

    __shared__ float s_in[8 * 18 * 19];
    float acc[8];
#pragma unroll
    for (int i = 0; i < 8; ++i) acc[i] = 0.f;

    for (int cc = 0; cc < CIN / 8; ++cc) {
        __syncthreads();
        for (int i = t; i < 8 * 324; i += 256) {
            int ci = i / 324, r = (i % 324) / 18, c = i % 18;
            int gy = iy0 + r, gx = ix0 + c;
            float v = 0.f;
            if ((unsigned)gy < 64u && (unsigned)gx < 64u)
                v = in[((b * CIN + cc * 8 + ci) * 64 + gy) * 64 + gx];
            s_in[(ci * 18 + r) * 19 + c] = v;
        }
        __syncthreads();
#pragma unroll
        for (int ci = 0; ci < 8; ++ci)
#pragma unroll
            for (int ky = 0; ky < 3; ++ky)
#pragma unroll
                for (int kx = 0; kx < 3; ++kx) {
                    float v = s_in[(ci * 18 + ty + ky) * 19 + tx + kx];
#pragma unroll
                    for (int co = 0; co < 8; ++co)
                        acc[co] += v * w[((cg * 8 + co) * CIN + cc * 8 + ci) * 9 + ky * 3 + kx];
                }
    }
#pragma unroll
    for (int co = 0; co < 8; ++co) {
        int oc = cg * 8 + co;
        float v = acc[co];
        if (HASBIAS) v += bias[oc];
        if (RELU) v = frelu(v);
        out[((b * COUT + oc) * 64 + oy0 + ty) * 64 + ox0 + tx] = v;
    }
}

// ---------------- residual 1x1: x += relu(conv1x1(t)), 32->128 ------------------
__global__ __launch_bounds__(256) void k_res1x1(const float* __restrict__ tin,
    const float* __restrict__ w, float* __restrict__ xbuf)
{
    int gid = blockIdx.x * 256 + threadIdx.x;   // 16 * 8 * 4096
    int px = gid & 4095;
    int cg = (gid >> 12) & 7;
    int b = gid >> 15;
    float acc[16];
#pragma unroll
    for (int i = 0; i < 16; ++i) acc[i] = 0.f;
#pragma unroll
    for (int ci = 0; ci < 32; ++ci) {
        float v = tin[(b * 32 + ci) * 4096 + px];
#pragma unroll
        for (int co = 0; co < 16; ++co)
            acc[co] += v * w[(cg * 16 + co) * 32 + ci];
    }
#pragma unroll
    for (int co = 0; co < 16; ++co) {
        int o = (b * 128 + cg * 16 + co) * 4096 + px;
        xbuf[o] = xbuf[o] + frelu(acc[co]);
    }
}

// ---------------- vector quantization: argmin + per-pixel min-dist --------------
__global__ __launch_bounds__(256) void k_vq(const float* __restrict__ z,
    const float* __restrict__ emb, int* __restrict__ idx, float* __restrict__ part)
{
    const int t = threadIdx.x;
    const int p = blockIdx.x * 256 + t;       // 0..65535
    const int b = p >> 12, h = (p >> 6) & 63, wq = p & 63;
    float zr[64];
#pragma unroll
    for (int d = 0; d < 64; ++d)
        zr[d] = z[((b * 64 + d) * 64 + h) * 64 + wq];

    __shared__ float se[64 * 64];
    float best = 3.4e38f;
    int bi = 0;
    for (int ch = 0; ch < 8; ++ch) {
        __syncthreads();
#pragma unroll
        for (int i = 0; i < 16; ++i)
            se[i * 256 + t] = emb[ch * 4096 + i * 256 + t];
        __syncthreads();
        for (int e = 0; e < 64; ++e) {
            float dist = 0.f;
#pragma unroll
            for (int d = 0; d < 64; ++d) {
                float diff = zr[d] - se[e * 64 + d];
                dist += diff * diff;
            }
            if (dist < best) { best = dist; bi = ch * 64 + e; }  // strict < -> first min
        }
    }
    idx[p] = bi;

    float s = best;
#pragma unroll
    for (int off = 32; off > 0; off >>= 1) s += __shfl_down(s, off, 64);
    __shared__ float sw[4];
    if ((t & 63) == 0) sw[t >> 6] = s;
    __syncthreads();
    if (t == 0) part[blockIdx.x] = sw[0] + sw[1] + sw[2] + sw[3];
}

__global__ __launch_bounds__(256) void k_qbuild(const int* __restrict__ idx,
    const float* __restrict__ emb, float* __restrict__ q)
{
    int i = blockIdx.x * 256 + threadIdx.x;   // 16*64*64*64
    int wq = i & 63;
    int h = (i >> 6) & 63;
    int d = (i >> 12) & 63;
    int b = i >> 18;
    int p = (b << 12) | (h << 6) | wq;
    q[i] = emb[idx[p] * 64 + d];
}

__global__ __launch_bounds__(256) void k_loss(const float* __restrict__ part, float* __restrict__ out)
{
    int t = threadIdx.x;
    float s = part[t];
#pragma unroll
    for (int off = 32; off > 0; off >>= 1) s += __shfl_down(s, off, 64);
    __shared__ float sw[4];
    if ((t & 63) == 0) sw[t >> 6] = s;
    __syncthreads();
    if (t == 0) out[3145728] = 1.25f * (sw[0] + sw[1] + sw[2] + sw[3]) / 4194304.0f;
}

// ---------------- ConvTranspose2d k4 s2 p1, relu; w layout (CIN,COUT,4,4) -------
template<int CIN, int COUT, int COT, int OW>
__global__ __launch_bounds__(256) void k_convT(const float* __restrict__ in,
    const float* __restrict__ w, const float* __restrict__ bias, float* __restrict__ out)
{
    const int IW = OW / 2;
    const int TPR = OW / 32;
    const int t = threadIdx.x;
    const int tile = blockIdx.x;              // TPR^2 tiles of 32x32 out
    const int NCG = COUT / COT;
    const int bcg = blockIdx.y;
    const int b = bcg / NCG, cg = bcg % NCG;
    const int oy0 = (tile / TPR) * 32, ox0 = (tile % TPR) * 32;
    const int tx = t & 15, ty = t >> 4;       // thread owns 2x2 out px
    const int iy0 = oy0 / 2 - 1, ix0 = ox0 / 2 - 1;

    __shared__ float s_in[8 * 18 * 19];
    float acc[4][COT];
#pragma unroll
    for (int a = 0; a < 4; ++a)
#pragma unroll
        for (int c = 0; c < COT; ++c) acc[a][c] = 0.f;

    for (int cc = 0; cc < CIN / 8; ++cc) {
        __syncthreads();
        for (int i = t; i < 8 * 324; i += 256) {
            int ci = i / 324, r = (i % 324) / 18, c = i % 18;
            int gy = iy0 + r, gx = ix0 + c;
            float v = 0.f;
            if ((unsigned)gy < (unsigned)IW && (unsigned)gx < (unsigned)IW)
                v = in[((b * CIN + cc * 8 + ci) * IW + gy) * IW + gx];
            s_in[(ci * 18 + r) * 19 + c] = v;
        }
        __syncthreads();
#pragma unroll
        for (int ci = 0; ci < 8; ++ci) {
            float rr[3][3];
#pragma unroll
            for (int dy = 0; dy < 3; ++dy)
#pragma unroll
                for (int dx = 0; dx < 3; ++dx)
                    rr[dy][dx] = s_in[(ci * 18 + ty + dy) * 19 + tx + dx];
#pragma unroll
            for (int ky = 0; ky < 4; ++ky) {
                const int py = 1 - (ky & 1);                    // out-y parity using this ky
                const int dy = (ky == 0) ? 2 : (ky == 3) ? 0 : 1;
#pragma unroll
                for (int kx = 0; kx < 4; ++kx) {
                    const int pxr = 1 - (kx & 1);
                    const int dx = (kx == 0) ? 2 : (kx == 3) ? 0 : 1;
                    float v = rr[dy][dx];
#pragma unroll
                    for (int co = 0; co < COT; ++co)
                        acc[py * 2 + pxr][co] +=
                            v * w[((cc * 8 + ci) * COUT + cg * COT + co) * 16 + ky * 4 + kx];
                }
            }
        }
    }
    const int ye = oy0 + 2 * ty, xe = ox0 + 2 * tx;
#pragma unroll
    for (int py = 0; py < 2; ++py)
#pragma unroll
        for (int pxr = 0; pxr < 2; ++pxr)
#pragma unroll
            for (int co = 0; co < COT; ++co) {
                int oc = cg * COT + co;
                out[((b * COUT + oc) * OW + ye + py) * OW + xe + pxr] =
                    frelu(acc[py * 2 + pxr][co] + bias[oc]);
            }
}

extern "C" void kernel_launch(void* const* d_in, const int* in_sizes, int n_in,
                              void* d_out, int out_size, void* d_ws, size_t ws_size,
                              hipStream_t stream)
{
    (void)in_sizes; (void)n_in; (void)out_size; (void)ws_size;
    const float* x    = (const float*)d_in[0];
    const float* emb  = (const float*)d_in[1];
    const float* ew1  = (const float*)d_in[2];
    const float* eb1  = (const float*)d_in[3];
    const float* ew2  = (const float*)d_in[4];
    const float* eb2  = (const float*)d_in[5];
    const float* er1a = (const float*)d_in[6];
    const float* er1b = (const float*)d_in[7];
    const float* er2a = (const float*)d_in[8];
    const float* er2b = (const float*)d_in[9];
    const float* ew3w = (const float*)d_in[10];
    const float* eb3  = (const float*)d_in[11];
    const float* dw1  = (const float*)d_in[12];
    const float* db1  = (const float*)d_in[13];
    const float* dr1a = (const float*)d_in[14];
    const float* dr1b = (const float*)d_in[15];
    const float* dr2a = (const float*)d_in[16];
    const float* dr2b = (const float*)d_in[17];
    const float* dtw1 = (const float*)d_in[18];
    const float* dtb1 = (const float*)d_in[19];
    const float* dtw2 = (const float*)d_in[20];
    const float* dtb2 = (const float*)d_in[21];
    float* out = (float*)d_out;
    float* ws  = (float*)d_ws;

    // A region [0, 16777216): h1, later reused for T/Z/Q/IDX/PART, finally upsample u1.
    float* A   = ws;
    float* Bf  = ws + 16777216;               // [16,128,64,64]
    float* T   = ws;                          // [16,32,64,64]  (h1 dead after ew2)
    float* Z   = ws + 2097152;                // [16,64,64,64]
    float* Q   = ws + 6291456;                // [16,64,64,64]
    int*   IDX = (int*)(ws + 10485760);       // 65536
    float* PART= ws + 10551296;               // 256

    k_ew1<<<dim3(64, 128), 256, 0, stream>>>(x, ew1, eb1, A);
    k_ew2<<<dim3(16, 256), 256, 0, stream>>>(A, ew2, eb2, Bf);
    k_conv3<128, 32, true, false><<<dim3(16, 64), 256, 0, stream>>>(Bf, er1a, nullptr, T);
    k_res1x1<<<2048, 256, 0, stream>>>(T, er1b, Bf);
    k_conv3<128, 32, true, false><<<dim3(16, 64), 256, 0, stream>>>(Bf, er2a, nullptr, T);
    k_res1x1<<<2048, 256, 0, stream>>>(T, er2b, Bf);
    k_conv3<128, 64, false, true><<<dim3(16, 128), 256, 0, stream>>>(Bf, ew3w, eb3, Z);
    k_vq<<<256, 256, 0, stream>>>(Z, emb, IDX, PART);
    k_qbuild<<<16384, 256, 0, stream>>>(IDX, emb, Q);
    k_loss<<<1, 256, 0, stream>>>(PART, out);
    k_conv3<64, 128, false, true><<<dim3(16, 256), 256, 0, stream>>>(Q, dw1, db1, Bf);
    k_conv3<128, 32, true, false><<<dim3(16, 64), 256, 0, stream>>>(Bf, dr1a, nullptr, T);
    k_res1x1<<<2048, 256, 0, stream>>>(T, dr1b, Bf);
    k_conv3<128, 32, true, false><<<dim3(16, 64), 256, 0, stream>>>(Bf, dr2a, nullptr, T);
    k_res1x1<<<2048, 256, 0, stream>>>(T, dr2b, Bf);
    k_convT<128, 64, 8, 128><<<dim3(16, 128), 256, 0, stream>>>(Bf, dtw1, dtb1, A);
    k_convT<64, 3, 3, 256><<<dim3(64, 16), 256, 0, stream>>>(A, dtw2, dtb2, out);
}